// Round 3
// baseline (121.319 us; speedup 1.0000x reference)
//
#include <hip/hip_runtime.h>

#define GH 52
#define GW 52
#define NB 5
#define NCELL (GH*GW)        // 2704
#define NBOX (NCELL*NB)      // 13520
#define SCALE 8.0f           // 416/52
#define NORMY 416.0f
#define IOU_T 0.4f

#define TS 4                 // decode interior tile; 52 % 4 == 0
#define HS (TS+2)
#define TBOX (HS*HS*NB)      // 180
#define NTX (GW/TS)          // 13
#define NTY (GH/TS)          // 13

#define KB 16                // score bands (band = f(score) only -> order-exact)
#define MASK45 ((1ull<<45)-1)
#define PW 54                // padded act grid (u32 per cell)
#define PCELLS (PW*PW)       // 2916
#define FCAP 192             // flagged-list slots per band
#define NT 256               // nms block = 4 waves

__device__ __forceinline__ int band16(float s) {
    int q = (int)(s * 16.0f);
    q = q < 0 ? 0 : (q > 15 ? 15 : q);
    return 15 - q;           // band 0 = highest scores
}

// ---- Kernel 1: fused decode + suppression-mask build (tile + halo in LDS) ----
// masks[j] (box-major): bits 0..44 predecessor mask (slot (dy+1)*15+(dx+1)*5+nb),
// bits 45..48 score band of j, bit 63 = "has a same-band predecessor" flag.
__global__ __launch_bounds__(192) void decode_adj_kernel(
        const float* __restrict__ x, float* __restrict__ out,
        unsigned long long* __restrict__ masks) {
    __shared__ float4 lbox[TBOX];
    __shared__ float  lsc[TBOX];
    int bx0 = (blockIdx.x % NTX) * TS;
    int by0 = (blockIdx.x / NTX) * TS;
    int t = threadIdx.x;

    if (t < TBOX) {
        int lcell = t / NB, b = t % NB;
        int lx = lcell % HS, ly = lcell / HS;
        int gx = bx0 + lx - 1, gy = by0 + ly - 1;
        float4 bb = make_float4(0.f, 0.f, 0.f, 0.f);
        float s = -1e30f;                       // sentinel: never a predecessor
        if (gx >= 0 && gx < GW && gy >= 0 && gy < GH) {
            const float* p = x + ((size_t)(gy * GW + gx) * NB + b) * 5;
            float c0 = p[0], c1 = p[1], c2 = p[2], c3 = p[3]; s = p[4];
            float cx = (c0 + (float)gx) * SCALE;
            float w  = c2 * SCALE;
            float cy = NORMY - (c1 + (float)gy) * SCALE;
            float h  = c3 * SCALE;
            bb = make_float4(cx - w * 0.5f, cy - h * 0.5f,
                             cx + w * 0.5f, cy + h * 0.5f);
        }
        lbox[t] = bb; lsc[t] = s;
    }
    __syncthreads();

    if (t < TS * TS * NB) {
        int lcell = t / NB, b = t % NB;
        int lxi = lcell % TS, lyi = lcell / TS;
        int gx = bx0 + lxi, gy = by0 + lyi;
        int lt = ((lyi + 1) * HS + (lxi + 1)) * NB + b;
        float4 bj = lbox[lt]; float sj = lsc[lt];
        int cell = gy * GW + gx;
        int j = cell * NB + b;
        int bdj = band16(sj);
        bool inb = false;
        float areaj = fmaxf(bj.z - bj.x, 0.f) * fmaxf(bj.w - bj.y, 0.f);
        unsigned long long m = 0ull;
        #pragma unroll
        for (int dy = -1; dy <= 1; ++dy)
        #pragma unroll
        for (int dx = -1; dx <= 1; ++dx)
        #pragma unroll
        for (int nb2 = 0; nb2 < NB; ++nb2) {
            int ln = ((lyi + 1 + dy) * HS + (lxi + 1 + dx)) * NB + nb2;
            int i = j + (dy * GW + dx) * NB + (nb2 - b);
            if (i == j) continue;
            float si = lsc[ln];
            // pri(i) > pri(j): score desc, stable-argsort index-asc tiebreak
            bool earlier = (si > sj) || (si == sj && i < j);
            if (!earlier) continue;
            float4 bi = lbox[ln];
            float iw = fmaxf(fminf(bi.z, bj.z) - fmaxf(bi.x, bj.x), 0.f);
            float ih = fmaxf(fminf(bi.w, bj.w) - fmaxf(bi.y, bj.y), 0.f);
            float inter = iw * ih;
            float areai = fmaxf(bi.z - bi.x, 0.f) * fmaxf(bi.w - bi.y, 0.f);
            float uni = areai + areaj - inter;
            float iou = (uni > 0.f) ? inter / fmaxf(uni, 1e-12f) : 0.f;
            if (iou > IOU_T) {
                m |= 1ull << ((dy + 1) * 15 + (dx + 1) * 5 + nb2);
                if (band16(si) == bdj) inb = true;   // same-band predecessor
            }
        }
        masks[j] = m | ((unsigned long long)bdj << 45)
                     | (inb ? (1ull << 63) : 0ull);
        out[j * 5 + 0] = bj.x; out[j * 5 + 1] = bj.y;
        out[j * 5 + 2] = bj.z; out[j * 5 + 3] = bj.w;
        out[j * 5 + 4] = sj;
    }
}

// eval: recompute active bit of box (p,b) from current act state; true if changed
__device__ __forceinline__ bool eval_box(volatile unsigned* A, unsigned e,
                                         unsigned long long m45) {
    int p = e & 0xFFF, b = (e >> 12) & 7;
    unsigned a00 = A[p - PW - 1], a01 = A[p - PW], a02 = A[p - PW + 1];
    unsigned a10 = A[p - 1],      a11 = A[p],      a12 = A[p + 1];
    unsigned a20 = A[p + PW - 1], a21 = A[p + PW], a22 = A[p + PW + 1];
    unsigned long long V = (unsigned long long)(a00 | (a01 << 5) | (a02 << 10))
        | ((unsigned long long)(a10 | (a11 << 5) | (a12 << 10)) << 15)
        | ((unsigned long long)(a20 | (a21 << 5) | (a22 << 10)) << 30);
    unsigned na = ((V & m45) == 0ull) ? 1u : 0u;
    unsigned old = (a11 >> b) & 1u;
    if (na != old) {
        if (na) atomicOr((unsigned*)(A + p), 1u << b);
        else    atomicAnd((unsigned*)(A + p), ~(1u << b));
        return true;
    }
    return false;
}

// ---- Kernel 2: score-banded exact NMS fixpoint --------------------------------
// Bands processed in descending score order. When band b runs, all predecessors
// in bands < b are final. Round 1 (256 threads) evaluates every band-b box with
// a nonempty mask once; only boxes flagged "same-band predecessor" can still be
// wrong, and wave 0 iterates exactly those to the local fixpoint (no barriers,
// wave-lockstep + __any). Exact by induction over bands; ties share a band.
__global__ __launch_bounds__(NT) void nms_kernel(
        const unsigned long long* __restrict__ masks,
        float* __restrict__ out) {
    __shared__ unsigned act[PCELLS];          // 5 active-bits per cell, padded
    __shared__ unsigned list[NBOX];           // band-major entries
    __shared__ unsigned flist[KB * FCAP];     // flagged entries per band
    __shared__ unsigned hcnt[4][KB];          // per-wave band histogram
    __shared__ unsigned hoff[4][KB];          // per-wave scatter cursors
    __shared__ unsigned fcnt[KB];
    __shared__ unsigned bstart[KB + 1];
    int t = threadIdx.x;
    int w = t >> 6, lane = t & 63;

    if (t < 4 * KB) ((unsigned*)hcnt)[t] = 0;
    if (t < KB) fcnt[t] = 0;
    for (int i = t; i < PCELLS; i += NT) {
        int py = i / PW, px = i - py * PW;
        act[i] = (py >= 1 && py <= GH && px >= 1 && px <= GW) ? 0x1Fu : 0u;
    }
    __syncthreads();

    // histogram (boxes with empty masks are never suppressed -> skip entirely)
    for (int j = t; j < NBOX; j += NT) {
        unsigned long long mm = masks[j];
        if (mm & MASK45) atomicAdd(&hcnt[w][(int)((mm >> 45) & 15)], 1u);
    }
    __syncthreads();

    // exclusive scan over (band, wave) in band-major order -> contiguous bands
    if (t < 64) {
        int bd = t >> 2, ww = t & 3;
        unsigned v = hcnt[ww][bd];
        unsigned acc = v;
        #pragma unroll
        for (int d = 1; d < 64; d <<= 1) {
            unsigned o = __shfl_up(acc, d);
            if (lane >= d) acc += o;
        }
        unsigned excl = acc - v;
        hoff[ww][bd] = excl;
        if (ww == 0) bstart[bd] = excl;
        if (t == 63) bstart[KB] = acc;
    }
    __syncthreads();

    // scatter: entry = padded cell index | box-slot | global box id
    for (int j = t; j < NBOX; j += NT) {
        unsigned long long mm = masks[j];
        if (!(mm & MASK45)) continue;
        int bd = (int)((mm >> 45) & 15);
        int cell = j / NB, b = j - cell * NB;
        int gy = cell / GW, gx = cell - gy * GW;
        unsigned e = (unsigned)((gy + 1) * PW + gx + 1)
                   | ((unsigned)b << 12) | ((unsigned)j << 15);
        unsigned pos = atomicAdd(&hoff[w][bd], 1u);
        list[pos] = e;
        if (mm >> 63) {
            unsigned fp = atomicAdd(&fcnt[bd], 1u);
            if (fp < FCAP) flist[bd * FCAP + fp] = e;
        }
    }
    __syncthreads();

    volatile unsigned* A = act;
    for (int bd = 0; bd < KB; ++bd) {
        int s0 = bstart[bd], s1 = bstart[bd + 1];
        // ---- round 1: all threads, loads prefetched to overlap latency ----
        unsigned ee[8]; unsigned long long mv[8]; int ne = 0;
        for (int k = s0 + t; k < s1 && ne < 8; k += NT) ee[ne++] = list[k];
        for (int i = 0; i < ne; ++i) mv[i] = masks[ee[i] >> 15] & MASK45;
        for (int i = 0; i < ne; ++i) eval_box(A, ee[i], mv[i]);
        for (int k = s0 + t + 8 * NT; k < s1; k += NT) {   // safety tail
            unsigned e = list[k];
            eval_box(A, e, masks[e >> 15] & MASK45);
        }
        __syncthreads();
        // ---- restricted rounds: wave 0 only, no barriers ----
        if (w == 0) {
            int fn = fcnt[bd];
            if (fn > FCAP) {
                // overflow fallback (practically unreachable): iterate whole band
                for (int rr = 0; rr < 1024; ++rr) {
                    bool ch = false;
                    for (int k = s0 + lane; k < s1; k += 64) {
                        unsigned e = list[k];
                        ch |= eval_box(A, e, masks[e >> 15] & MASK45);
                    }
                    if (!__any(ch)) break;
                }
            } else if (fn > 0) {
                unsigned fe[3]; unsigned long long fm[3]; int nf = 0;
                for (int k = lane; k < fn && nf < 3; k += 64)
                    fe[nf++] = flist[bd * FCAP + k];
                for (int i = 0; i < nf; ++i) fm[i] = masks[fe[i] >> 15] & MASK45;
                for (int rr = 0; rr < 256; ++rr) {         // cap > FCAP+2 -> exact
                    bool ch = false;
                    for (int i = 0; i < nf; ++i) ch |= eval_box(A, fe[i], fm[i]);
                    if (!__any(ch)) break;
                }
            }
        }
        __syncthreads();
    }

    // writeback: zero scores of suppressed boxes (coords+scores written by k1)
    for (int c = t; c < NCELL; c += NT) {
        int gy = c / GW, gx = c - gy * GW;
        unsigned bits = act[(gy + 1) * PW + gx + 1];
        #pragma unroll
        for (int b = 0; b < NB; ++b)
            if (!((bits >> b) & 1u)) out[(c * NB + b) * 5 + 4] = 0.0f;
    }
}

extern "C" void kernel_launch(void* const* d_in, const int* in_sizes, int n_in,
                              void* d_out, int out_size, void* d_ws, size_t ws_size,
                              hipStream_t stream) {
    const float* x = (const float*)d_in[0];
    float* out = (float*)d_out;

    // ws layout: masks u64[NBOX] box-major (108160 B)
    unsigned long long* masks = (unsigned long long*)d_ws;

    decode_adj_kernel<<<NTX * NTY, 192, 0, stream>>>(x, out, masks);
    nms_kernel<<<1, NT, 0, stream>>>(masks, out);
}

// Round 4
// 120.201 us; speedup vs baseline: 1.0093x; 1.0093x over previous
//
#include <hip/hip_runtime.h>

#define GH 52
#define GW 52
#define NB 5
#define NCELL (GH*GW)        // 2704
#define NBOX (NCELL*NB)      // 13520
#define SCALE 8.0f           // 416/52
#define NORMY 416.0f
#define IOU_T 0.4f

#define TS 4                 // decode interior tile; 52 % 4 == 0
#define HS (TS+2)
#define TBOX (HS*HS*NB)      // 180
#define NTX (GW/TS)          // 13
#define NTY (GH/TS)          // 13

#define KB 16                // score bands (band = f(score) only -> order-exact)
#define MASK45 ((1ull<<45)-1)

// ---- nms geometry: strip-owned, aligned-window act grid (round-1 proven) ----
#define PW2 56               // padded act row stride; window base 56*row+4*s is 4B-aligned
#define PR  54               // padded rows
#define PC2 (PR*PW2)         // 3024 B
#define NSTRIP 13            // 4-cell strips per row
#define NTHR (GH*NSTRIP)     // 676 workers
#define BLK 704              // 11 waves

__device__ __forceinline__ int band16(float s) {
    int q = (int)(s * 16.0f);
    q = q < 0 ? 0 : (q > 15 ? 15 : q);
    return 15 - q;           // band 0 = highest scores
}

// ---- Kernel 1: fused decode + suppression-mask build (tile + halo in LDS) ----
// masks[j] (box-major): bits 0..44 predecessor mask (slot (dy+1)*15+(dx+1)*5+nb),
// bits 45..48 score band of j, bit 63 = "has same-band predecessor".
__global__ __launch_bounds__(192) void decode_adj_kernel(
        const float* __restrict__ x, float* __restrict__ out,
        unsigned long long* __restrict__ masks) {
    __shared__ float4 lbox[TBOX];
    __shared__ float  lsc[TBOX];
    int bx0 = (blockIdx.x % NTX) * TS;
    int by0 = (blockIdx.x / NTX) * TS;
    int t = threadIdx.x;

    if (t < TBOX) {
        int lcell = t / NB, b = t % NB;
        int lx = lcell % HS, ly = lcell / HS;
        int gx = bx0 + lx - 1, gy = by0 + ly - 1;
        float4 bb = make_float4(0.f, 0.f, 0.f, 0.f);
        float s = -1e30f;                       // sentinel: never a predecessor
        if (gx >= 0 && gx < GW && gy >= 0 && gy < GH) {
            const float* p = x + ((size_t)(gy * GW + gx) * NB + b) * 5;
            float c0 = p[0], c1 = p[1], c2 = p[2], c3 = p[3]; s = p[4];
            float cx = (c0 + (float)gx) * SCALE;
            float w  = c2 * SCALE;
            float cy = NORMY - (c1 + (float)gy) * SCALE;
            float h  = c3 * SCALE;
            bb = make_float4(cx - w * 0.5f, cy - h * 0.5f,
                             cx + w * 0.5f, cy + h * 0.5f);
        }
        lbox[t] = bb; lsc[t] = s;
    }
    __syncthreads();

    if (t < TS * TS * NB) {
        int lcell = t / NB, b = t % NB;
        int lxi = lcell % TS, lyi = lcell / TS;
        int gx = bx0 + lxi, gy = by0 + lyi;
        int lt = ((lyi + 1) * HS + (lxi + 1)) * NB + b;
        float4 bj = lbox[lt]; float sj = lsc[lt];
        int cell = gy * GW + gx;
        int j = cell * NB + b;
        int bdj = band16(sj);
        bool inb = false;
        float areaj = fmaxf(bj.z - bj.x, 0.f) * fmaxf(bj.w - bj.y, 0.f);
        unsigned long long m = 0ull;
        #pragma unroll
        for (int dy = -1; dy <= 1; ++dy)
        #pragma unroll
        for (int dx = -1; dx <= 1; ++dx)
        #pragma unroll
        for (int nb2 = 0; nb2 < NB; ++nb2) {
            int ln = ((lyi + 1 + dy) * HS + (lxi + 1 + dx)) * NB + nb2;
            int i = j + (dy * GW + dx) * NB + (nb2 - b);
            if (i == j) continue;
            float si = lsc[ln];
            // pri(i) > pri(j): score desc, stable-argsort index-asc tiebreak
            bool earlier = (si > sj) || (si == sj && i < j);
            if (!earlier) continue;
            float4 bi = lbox[ln];
            float iw = fmaxf(fminf(bi.z, bj.z) - fmaxf(bi.x, bj.x), 0.f);
            float ih = fmaxf(fminf(bi.w, bj.w) - fmaxf(bi.y, bj.y), 0.f);
            float inter = iw * ih;
            float areai = fmaxf(bi.z - bi.x, 0.f) * fmaxf(bi.w - bi.y, 0.f);
            float uni = areai + areaj - inter;
            float iou = (uni > 0.f) ? inter / fmaxf(uni, 1e-12f) : 0.f;
            if (iou > IOU_T) {
                m |= 1ull << ((dy + 1) * 15 + (dx + 1) * 5 + nb2);
                if (band16(si) == bdj) inb = true;   // same-band predecessor
            }
        }
        masks[j] = m | ((unsigned long long)bdj << 45)
                     | (inb ? (1ull << 63) : 0ull);
        out[j * 5 + 0] = bj.x; out[j * 5 + 1] = bj.y;
        out[j * 5 + 2] = bj.z; out[j * 5 + 3] = bj.w;
        out[j * 5 + 4] = sj;
    }
}

// ---- Kernel 2: banded exact NMS fixpoint, list-free --------------------------
// Strip-owned (round-1 structure): thread owns 4 cells x 5 boxes, masks in
// registers. Bands descend in score order; when band bd runs, all earlier-band
// states are final. Round 0 of a band evaluates every owned band-bd box once;
// rounds >=1 re-evaluate only boxes flagged "same-band predecessor" (bit 63),
// until a zero-change round (__syncthreads_count==0): no concurrent writes in
// that round -> reads consistent -> band sub-DAG at its unique fixpoint. Exact
// by induction over bands. No lists, no LDS atomics, no volatile chains.
__global__ __launch_bounds__(BLK) void nms_kernel(
        const unsigned long long* __restrict__ masks,
        float* __restrict__ out) {
    __shared__ __align__(8) unsigned char act_s[PC2];
    int t = threadIdx.x;
    bool wk = t < NTHR;
    int row = t / NSTRIP;            // 0..51
    int s   = t - row * NSTRIP;      // 0..12
    int gx0 = s * 4;
    int cell0 = row * GW + gx0;

    // owned masks -> registers: 20 consecutive u64 per thread (box-major)
    unsigned long long cm[4][NB];
    #pragma unroll
    for (int c = 0; c < 4; ++c)
        #pragma unroll
        for (int b = 0; b < NB; ++b)
            cm[c][b] = wk ? masks[(cell0 + c) * NB + b] : 0ull;

    // per-band participation masks (round0: any evaluable box; round>=1: bit63)
    unsigned p0m = 0, p1m = 0;
    #pragma unroll
    for (int c = 0; c < 4; ++c)
        #pragma unroll
        for (int b = 0; b < NB; ++b) {
            unsigned long long m = cm[c][b];
            if (m & MASK45) {
                int bd = (int)((m >> 45) & 15);
                p0m |= 1u << bd;
                if (m >> 63) p1m |= 1u << bd;
            }
        }

    // init act grid: interior 0x1F (all active), padding 0
    for (int i = t; i < PC2; i += BLK) {
        int py = i / PW2, px = i - py * PW2;
        act_s[i] = (py >= 1 && py <= GH && px >= 1 && px <= GW) ? 0x1F : 0;
    }
    __syncthreads();

    int p0 = row * PW2 + gx0;            // 4B-aligned window base (rows row-1..row+1)
    int pc = (row + 1) * PW2 + gx0 + 1;  // own cells' first byte

    auto rdrow = [&](int p) -> unsigned {
        unsigned lo = *(const unsigned int*)(act_s + p);
        unsigned hi = *(const unsigned short*)(act_s + p + 4);
        return (lo & 0x1F)
             | (((lo >> 8)  & 0x1F) << 5)
             | (((lo >> 16) & 0x1F) << 10)
             | (((lo >> 24) & 0x1F) << 15)
             | ((hi & 0x1F) << 20)
             | (((hi >> 8) & 0x1F) << 25);
    };

    for (int bd = 0; bd < KB; ++bd) {
        for (int r = 0; r < 128; ++r) {
            bool mych = false;
            bool part = wk && (((r == 0 ? p0m : p1m) >> bd) & 1u);
            if (part) {
                unsigned r0  = rdrow(p0);
                unsigned r1v = rdrow(p0 + PW2);
                unsigned r2  = rdrow(p0 + 2 * PW2);
                #pragma unroll
                for (int c = 0; c < 4; ++c) {
                    bool cch = false;
                    #pragma unroll
                    for (int b = 0; b < NB; ++b) {
                        unsigned long long m = cm[c][b];
                        if (!(m & MASK45)) continue;
                        if ((int)((m >> 45) & 15) != bd) continue;
                        if (r > 0 && !(m >> 63)) continue;
                        unsigned long long V =
                              (unsigned long long)((r0  >> (5 * c)) & 0x7FFF)
                            | ((unsigned long long)((r1v >> (5 * c)) & 0x7FFF) << 15)
                            | ((unsigned long long)((r2  >> (5 * c)) & 0x7FFF) << 30);
                        unsigned na = ((V & (m & MASK45)) == 0ull) ? 1u : 0u;
                        unsigned pos = 5u * (c + 1) + b;
                        if (na != ((r1v >> pos) & 1u)) {
                            r1v ^= 1u << pos;       // in-thread Gauss-Seidel
                            cch = true;
                        }
                    }
                    if (cch) {
                        act_s[pc + c] = (unsigned char)((r1v >> (5 * (c + 1))) & 0x1F);
                        mych = true;
                    }
                }
            }
            if (__syncthreads_count(mych ? 1 : 0) == 0) break;
        }
    }

    // writeback: zero scores of suppressed boxes (coords+scores written by k1)
    if (wk) {
        #pragma unroll
        for (int c = 0; c < 4; ++c) {
            unsigned bits = act_s[pc + c];
            #pragma unroll
            for (int b = 0; b < NB; ++b)
                if (!((bits >> b) & 1u)) out[((cell0 + c) * NB + b) * 5 + 4] = 0.0f;
        }
    }
}

extern "C" void kernel_launch(void* const* d_in, const int* in_sizes, int n_in,
                              void* d_out, int out_size, void* d_ws, size_t ws_size,
                              hipStream_t stream) {
    const float* x = (const float*)d_in[0];
    float* out = (float*)d_out;

    // ws layout: masks u64[NBOX] box-major (108160 B)
    unsigned long long* masks = (unsigned long long*)d_ws;

    decode_adj_kernel<<<NTX * NTY, 192, 0, stream>>>(x, out, masks);
    nms_kernel<<<1, BLK, 0, stream>>>(masks, out);
}

// Round 5
// 98.547 us; speedup vs baseline: 1.2311x; 1.2197x over previous
//
#include <hip/hip_runtime.h>

#define GH 52
#define GW 52
#define NB 5
#define NCELL (GH*GW)        // 2704
#define NBOX (NCELL*NB)      // 13520
#define SCALE 8.0f           // 416/52
#define NORMY 416.0f
#define IOU_T 0.4f

#define TS 4                 // decode interior tile; 52 % 4 == 0
#define HS (TS+2)
#define TBOX (HS*HS*NB)      // 180
#define NTX (GW/TS)          // 13
#define NTY (GH/TS)          // 13

#define KB 8                 // score bands (band = f(score) only -> order-exact)
#define MASK45 ((1ull<<45)-1)

// ---- nms geometry: strip-owned, aligned-window act grid ----
#define PW2 56               // padded act row stride; window base 56*row+4*s is 4B-aligned
#define PR  54               // padded rows
#define PC2 (PR*PW2)         // 3024 B
#define NSTRIP 13            // 4-cell strips per row
#define NTHR (GH*NSTRIP)     // 676 workers
#define BLK 704              // 11 waves

__device__ __forceinline__ int band8(float s) {
    int q = (int)(s * 8.0f);
    q = q < 0 ? 0 : (q > 7 ? 7 : q);
    return 7 - q;            // band 0 = highest scores
}

// ---- Kernel 1: fused decode + suppression-mask build (tile + halo in LDS) ----
// masks[j] (box-major): bits 0..44 predecessor mask (slot (dy+1)*15+(dx+1)*5+nb),
// bits 45..47 score band of j, bit 63 = "has same-band predecessor".
__global__ __launch_bounds__(192) void decode_adj_kernel(
        const float* __restrict__ x, float* __restrict__ out,
        unsigned long long* __restrict__ masks) {
    __shared__ float4 lbox[TBOX];
    __shared__ float  lsc[TBOX];
    int bx0 = (blockIdx.x % NTX) * TS;
    int by0 = (blockIdx.x / NTX) * TS;
    int t = threadIdx.x;

    if (t < TBOX) {
        int lcell = t / NB, b = t % NB;
        int lx = lcell % HS, ly = lcell / HS;
        int gx = bx0 + lx - 1, gy = by0 + ly - 1;
        float4 bb = make_float4(0.f, 0.f, 0.f, 0.f);
        float s = -1e30f;                       // sentinel: never a predecessor
        if (gx >= 0 && gx < GW && gy >= 0 && gy < GH) {
            const float* p = x + ((size_t)(gy * GW + gx) * NB + b) * 5;
            float c0 = p[0], c1 = p[1], c2 = p[2], c3 = p[3]; s = p[4];
            float cx = (c0 + (float)gx) * SCALE;
            float w  = c2 * SCALE;
            float cy = NORMY - (c1 + (float)gy) * SCALE;
            float h  = c3 * SCALE;
            bb = make_float4(cx - w * 0.5f, cy - h * 0.5f,
                             cx + w * 0.5f, cy + h * 0.5f);
        }
        lbox[t] = bb; lsc[t] = s;
    }
    __syncthreads();

    if (t < TS * TS * NB) {
        int lcell = t / NB, b = t % NB;
        int lxi = lcell % TS, lyi = lcell / TS;
        int gx = bx0 + lxi, gy = by0 + lyi;
        int lt = ((lyi + 1) * HS + (lxi + 1)) * NB + b;
        float4 bj = lbox[lt]; float sj = lsc[lt];
        int cell = gy * GW + gx;
        int j = cell * NB + b;
        int bdj = band8(sj);
        bool inb = false;
        float areaj = fmaxf(bj.z - bj.x, 0.f) * fmaxf(bj.w - bj.y, 0.f);
        unsigned long long m = 0ull;
        #pragma unroll
        for (int dy = -1; dy <= 1; ++dy)
        #pragma unroll
        for (int dx = -1; dx <= 1; ++dx)
        #pragma unroll
        for (int nb2 = 0; nb2 < NB; ++nb2) {
            int ln = ((lyi + 1 + dy) * HS + (lxi + 1 + dx)) * NB + nb2;
            int i = j + (dy * GW + dx) * NB + (nb2 - b);
            if (i == j) continue;
            float si = lsc[ln];
            // pri(i) > pri(j): score desc, stable-argsort index-asc tiebreak
            bool earlier = (si > sj) || (si == sj && i < j);
            if (!earlier) continue;
            float4 bi = lbox[ln];
            float iw = fmaxf(fminf(bi.z, bj.z) - fmaxf(bi.x, bj.x), 0.f);
            float ih = fmaxf(fminf(bi.w, bj.w) - fmaxf(bi.y, bj.y), 0.f);
            float inter = iw * ih;
            float areai = fmaxf(bi.z - bi.x, 0.f) * fmaxf(bi.w - bi.y, 0.f);
            float uni = areai + areaj - inter;
            float iou = (uni > 0.f) ? inter / fmaxf(uni, 1e-12f) : 0.f;
            if (iou > IOU_T) {
                m |= 1ull << ((dy + 1) * 15 + (dx + 1) * 5 + nb2);
                if (band8(si) == bdj) inb = true;   // same-band predecessor
            }
        }
        masks[j] = m | ((unsigned long long)bdj << 45)
                     | (inb ? (1ull << 63) : 0ull);
        out[j * 5 + 0] = bj.x; out[j * 5 + 1] = bj.y;
        out[j * 5 + 2] = bj.z; out[j * 5 + 3] = bj.w;
        out[j * 5 + 4] = sj;
    }
}

// ---- Kernel 2: pipelined band-frontier exact NMS fixpoint -------------------
// Frontier at band bd: each round evaluates A = {flagged boxes of band bd} and
// B = {all with-pred boxes of band bd+1}. Advance bd when fA==0 for a round:
// A-evals read only bands<=bd; the only writes to bands<=bd are A-writes, so a
// zero-A round has consistent reads -> bands<=bd at fixpoint (final). The same
// round's B-evals of UNFLAGGED bd+1 boxes (preds strictly in bands<=bd) thus
// read final values -> exact, never re-evaluated. Flagged bd+1 boxes continue
// as next state's A-set. Exact by induction; rounds ~ KB+1 + flagged chains.
__global__ __launch_bounds__(BLK) void nms_kernel(
        const unsigned long long* __restrict__ masks,
        float* __restrict__ out) {
    __shared__ __align__(8) unsigned char act_s[PC2];
    __shared__ unsigned fA[3];               // 3-slot rotation: 1 barrier/round
    int t = threadIdx.x;
    bool wk = t < NTHR;
    int row = t / NSTRIP;            // 0..51
    int s   = t - row * NSTRIP;      // 0..12
    int gx0 = s * 4;
    int cell0 = row * GW + gx0;

    // owned masks -> registers; band codes (4b/box), flagged bits, and per-band
    // per-cell membership bitmaps cb0 (any with-pred box) / cb1 (flagged box).
    unsigned long long cm[4][NB];
    unsigned bc[4] = {0, 0, 0, 0}, fl[4] = {0, 0, 0, 0};
    unsigned cb0 = 0, cb1 = 0;
    #pragma unroll
    for (int c = 0; c < 4; ++c)
        #pragma unroll
        for (int b = 0; b < NB; ++b) {
            unsigned long long m = wk ? masks[(cell0 + c) * NB + b] : 0ull;
            unsigned bd = (unsigned)((m >> 45) & 7);
            bool has = (m & MASK45) != 0ull;
            bool fg  = (m >> 63) != 0ull;
            cm[c][b] = m & MASK45;
            bc[c] |= (has ? bd : 15u) << (4 * b);
            if (has) cb0 |= 1u << (bd * 4 + c);
            if (has && fg) { fl[c] |= 1u << b; cb1 |= 1u << (bd * 4 + c); }
        }

    // init act grid: interior 0x1F (all active), padding 0
    for (int i = t; i < PC2; i += BLK) {
        int py = i / PW2, px = i - py * PW2;
        act_s[i] = (py >= 1 && py <= GH && px >= 1 && px <= GW) ? 0x1F : 0;
    }
    if (t < 3) fA[t] = 0;
    __syncthreads();

    int p0 = row * PW2 + gx0;            // 4B-aligned window base (rows row-1..row+1)
    int pc = (row + 1) * PW2 + gx0 + 1;  // own cells' first byte

    auto rdrow = [&](int p) -> unsigned {
        unsigned lo = *(const unsigned int*)(act_s + p);
        unsigned hi = *(const unsigned short*)(act_s + p + 4);
        return (lo & 0x1F)
             | (((lo >> 8)  & 0x1F) << 5)
             | (((lo >> 16) & 0x1F) << 10)
             | (((lo >> 24) & 0x1F) << 15)
             | ((hi & 0x1F) << 20)
             | (((hi >> 8) & 0x1F) << 25);
    };

    int sw = 0;                          // current write/read slot
    int bd = -1;                         // frontier band
    for (int r = 0; r < 400 && bd < KB; ++r) {
        int swn = sw + 1; if (swn == 3) swn = 0;
        if (t == 0) fA[swn] = 0;         // clear next slot (not read/written now)
        bool myA = false;
        if (wk) {
            unsigned am = (bd >= 0)     ? ((cb1 >> (bd * 4)) & 0xFu) : 0u;
            unsigned bm = (bd + 1 < KB) ? ((cb0 >> ((bd + 1) * 4)) & 0xFu) : 0u;
            unsigned cmask = am | bm;
            if (cmask) {
                unsigned r0  = rdrow(p0);
                unsigned r1v = rdrow(p0 + PW2);
                unsigned r2  = rdrow(p0 + 2 * PW2);
                #pragma unroll
                for (int c = 0; c < 4; ++c) {
                    if (!((cmask >> c) & 1u)) continue;
                    unsigned long long Vlh =
                          (unsigned long long)((r0 >> (5 * c)) & 0x7FFF)
                        | ((unsigned long long)((r2 >> (5 * c)) & 0x7FFF) << 30);
                    bool cch = false;
                    #pragma unroll
                    for (int b = 0; b < NB; ++b) {
                        int bb = (int)((bc[c] >> (4 * b)) & 15u);
                        bool isA = (bb == bd) && ((fl[c] >> b) & 1u);
                        bool isB = (bb == bd + 1);
                        if (!(isA || isB)) continue;
                        unsigned long long V = Vlh
                            | ((unsigned long long)((r1v >> (5 * c)) & 0x7FFF) << 15);
                        unsigned na = ((V & cm[c][b]) == 0ull) ? 1u : 0u;
                        unsigned pos = 5u * (c + 1) + b;
                        if (na != ((r1v >> pos) & 1u)) {
                            r1v ^= 1u << pos;       // in-thread Gauss-Seidel
                            cch = true;
                            if (isA) myA = true;
                        }
                    }
                    if (cch)
                        act_s[pc + c] = (unsigned char)((r1v >> (5 * (c + 1))) & 0x1F);
                }
            }
        }
        if (myA) fA[sw] = 1u;            // benign all-write-1 race
        __syncthreads();
        unsigned a = fA[sw];             // uniform read after barrier
        sw = swn;
        if (a == 0) ++bd;                // bands<=bd final; bd+1 unflagged certified
    }

    // writeback: zero scores of suppressed boxes (coords+scores written by k1)
    if (wk) {
        #pragma unroll
        for (int c = 0; c < 4; ++c) {
            unsigned bits = act_s[pc + c];
            #pragma unroll
            for (int b = 0; b < NB; ++b)
                if (!((bits >> b) & 1u)) out[((cell0 + c) * NB + b) * 5 + 4] = 0.0f;
        }
    }
}

extern "C" void kernel_launch(void* const* d_in, const int* in_sizes, int n_in,
                              void* d_out, int out_size, void* d_ws, size_t ws_size,
                              hipStream_t stream) {
    const float* x = (const float*)d_in[0];
    float* out = (float*)d_out;

    // ws layout: masks u64[NBOX] box-major (108160 B)
    unsigned long long* masks = (unsigned long long*)d_ws;

    decode_adj_kernel<<<NTX * NTY, 192, 0, stream>>>(x, out, masks);
    nms_kernel<<<1, BLK, 0, stream>>>(masks, out);
}

// Round 6
// 75.563 us; speedup vs baseline: 1.6055x; 1.3042x over previous
//
#include <hip/hip_runtime.h>

#define GH 52
#define GW 52
#define NB 5
#define NCELL (GH*GW)        // 2704
#define NBOX (NCELL*NB)      // 13520
#define SCALE 8.0f           // 416/52
#define NORMY 416.0f
#define IOU_T 0.4f

#define TS 4                 // decode interior tile; 52 % 4 == 0
#define HS (TS+2)
#define TBOX (HS*HS*NB)      // 180
#define NTX (GW/TS)          // 13
#define NTY (GH/TS)          // 13

// ---- nms geometry: 4-wide x 2-tall tiles, aligned-window act grid ----
#define PW2 56               // padded act row stride; window base is 4B-aligned
#define PR  54               // padded rows
#define PC2 (PR*PW2)         // 3024 B
#define TW 13                // tiles across (4 cells each)
#define THT 26               // tiles down (2 cells each)
#define NTIL (TW*THT)        // 338 workers
#define BLK2 384             // 6 waves

// ---- Kernel 1: fused decode + suppression-mask build (round-0 proven) -------
// For box j, predecessors (higher priority: score desc, index asc; IoU>0.4) all
// lie in the 3x3 cell neighborhood -> 45 slots -> one u64 bitmask per box.
// Slot layout: bit (dy+1)*15 + (dx+1)*5 + nb2 (matches nms V-vector build).
// Masks stored plane-major: masks[b*NCELL + cell].
__global__ __launch_bounds__(192) void decode_adj_kernel(
        const float* __restrict__ x, float* __restrict__ out,
        unsigned long long* __restrict__ masks) {
    __shared__ float4 lbox[TBOX];
    __shared__ float  lsc[TBOX];
    int bx0 = (blockIdx.x % NTX) * TS;
    int by0 = (blockIdx.x / NTX) * TS;
    int t = threadIdx.x;

    if (t < TBOX) {
        int lcell = t / NB, b = t % NB;
        int lx = lcell % HS, ly = lcell / HS;
        int gx = bx0 + lx - 1, gy = by0 + ly - 1;
        float4 bb = make_float4(0.f, 0.f, 0.f, 0.f);
        float s = -1e30f;                       // sentinel: never a predecessor
        if (gx >= 0 && gx < GW && gy >= 0 && gy < GH) {
            const float* p = x + ((size_t)(gy * GW + gx) * NB + b) * 5;
            float c0 = p[0], c1 = p[1], c2 = p[2], c3 = p[3]; s = p[4];
            float cx = (c0 + (float)gx) * SCALE;
            float w  = c2 * SCALE;
            float cy = NORMY - (c1 + (float)gy) * SCALE;
            float h  = c3 * SCALE;
            bb = make_float4(cx - w * 0.5f, cy - h * 0.5f,
                             cx + w * 0.5f, cy + h * 0.5f);
        }
        lbox[t] = bb; lsc[t] = s;
    }
    __syncthreads();

    if (t < TS * TS * NB) {
        int lcell = t / NB, b = t % NB;
        int lxi = lcell % TS, lyi = lcell / TS;
        int gx = bx0 + lxi, gy = by0 + lyi;
        int lt = ((lyi + 1) * HS + (lxi + 1)) * NB + b;
        float4 bj = lbox[lt]; float sj = lsc[lt];
        int cell = gy * GW + gx;
        int j = cell * NB + b;
        float areaj = fmaxf(bj.z - bj.x, 0.f) * fmaxf(bj.w - bj.y, 0.f);
        unsigned long long m = 0ull;
        #pragma unroll
        for (int dy = -1; dy <= 1; ++dy)
        #pragma unroll
        for (int dx = -1; dx <= 1; ++dx)
        #pragma unroll
        for (int nb2 = 0; nb2 < NB; ++nb2) {
            int ln = ((lyi + 1 + dy) * HS + (lxi + 1 + dx)) * NB + nb2;
            int i = j + (dy * GW + dx) * NB + (nb2 - b);
            if (i == j) continue;
            float si = lsc[ln];
            // pri(i) > pri(j): score desc, stable-argsort index-asc tiebreak
            bool earlier = (si > sj) || (si == sj && i < j);
            if (!earlier) continue;
            float4 bi = lbox[ln];
            float iw = fmaxf(fminf(bi.z, bj.z) - fmaxf(bi.x, bj.x), 0.f);
            float ih = fmaxf(fminf(bi.w, bj.w) - fmaxf(bi.y, bj.y), 0.f);
            float inter = iw * ih;
            float areai = fmaxf(bi.z - bi.x, 0.f) * fmaxf(bi.w - bi.y, 0.f);
            float uni = areai + areaj - inter;
            float iou = (uni > 0.f) ? inter / fmaxf(uni, 1e-12f) : 0.f;
            if (iou > IOU_T)
                m |= 1ull << ((dy + 1) * 15 + (dx + 1) * 5 + nb2);
        }
        masks[b * NCELL + cell] = m;
        out[j * 5 + 0] = bj.x; out[j * 5 + 1] = bj.y;
        out[j * 5 + 2] = bj.z; out[j * 5 + 3] = bj.w;
        out[j * 5 + 4] = sj;
    }
}

// ---- Kernel 2: chaotic fixpoint, 4x2-tile Gauss-Seidel ---------------------
// Thread owns a 4-wide x 2-tall cell tile; in-register Gauss-Seidel over the
// 8 cells (sweep direction cycles over 4 diagonals by pass) gives 4 cells/pass
// horizontal and 2/pass vertical propagation (round-1 was 4/1 -> vertical-
// limited ~80 passes). Row-dirty gating (exact) + 3-buffer flag rotation +
// single __syncthreads_count per pass -- all proven in rounds 0/1. Chaotic
// iteration on the acyclic priority DAG converges to the unique fixpoint
// (= exact greedy NMS); a zero-change gated pass certifies it as before.
__global__ __launch_bounds__(BLK2) void nms_kernel(
        const unsigned long long* __restrict__ masks,
        float* __restrict__ out) {
    __shared__ __align__(8) unsigned char act_s[PC2];
    __shared__ unsigned int rowflag[3][PR];
    int t = threadIdx.x;
    bool wk = t < NTIL;
    int tr = t / TW, tc = t - tr * TW;   // tile row 0..25, tile col 0..12
    int gy0 = 2 * tr, gx0 = 4 * tc;

    // owned masks -> registers: cm[i][j][b], 40 u64 (plane-major global layout)
    unsigned long long cm[2][4][NB];
    #pragma unroll
    for (int i = 0; i < 2; ++i)
        #pragma unroll
        for (int j = 0; j < 4; ++j)
            #pragma unroll
            for (int b = 0; b < NB; ++b)
                cm[i][j][b] = wk ? masks[b * NCELL + (gy0 + i) * GW + gx0 + j] : 0ull;

    // init act grid: interior 0x1F (all active), padding 0
    for (int i = t; i < PC2; i += BLK2) {
        int py = i / PW2, px = i - py * PW2;
        act_s[i] = (py >= 1 && py <= GH && px >= 1 && px <= GW) ? 0x1F : 0;
    }
    if (t < PR) {
        rowflag[0][t] = 0;
        rowflag[1][t] = 0;
        rowflag[2][t] = (t >= 1 && t <= GH) ? 1u : 0u;   // prev for pass 0: all dirty
    }
    __syncthreads();

    // window: global rows gy0-1..gy0+2 (padded gy0..gy0+3), cols gx0-1..gx0+4
    // base byte (gy0+k)*56 + gx0 is 4B-aligned (gy0 even, gx0 mult of 4)
    int p0  = gy0 * PW2 + gx0;
    int pcB = (gy0 + 1) * PW2 + gx0 + 1;     // own top-left cell byte

    auto rdrow = [&](int p) -> unsigned {
        unsigned lo = *(const unsigned int*)(act_s + p);
        unsigned hi = *(const unsigned short*)(act_s + p + 4);
        return (lo & 0x1F)
             | (((lo >> 8)  & 0x1F) << 5)
             | (((lo >> 16) & 0x1F) << 10)
             | (((lo >> 24) & 0x1F) << 15)
             | ((hi & 0x1F) << 20)
             | (((hi >> 8) & 0x1F) << 25);
    };

    int pprev = 2, pcur = 0, pnext = 1;
    for (int pass = 0; pass < 256; ++pass) {
        if (t < PR) rowflag[pnext][t] = 0;   // clear next buffer (not used this pass)
        const unsigned int* prevf = rowflag[pprev];
        bool mych = false;
        if (wk && ((prevf[gy0] | prevf[gy0 + 1] | prevf[gy0 + 2] | prevf[gy0 + 3]) != 0u)) {
            unsigned wr[4];
            wr[0] = rdrow(p0);
            wr[1] = rdrow(p0 + PW2);
            wr[2] = rdrow(p0 + 2 * PW2);
            wr[3] = rdrow(p0 + 3 * PW2);
            bool rch0 = false, rch1 = false;

            // EVAL(I,J): all indices literal -> registers only (no scratch)
            #define EVAL(I, J) do {                                             \
                unsigned long long V =                                          \
                      (unsigned long long)((wr[(I)]     >> (5 * (J))) & 0x7FFF) \
                    | ((unsigned long long)((wr[(I)+1] >> (5 * (J))) & 0x7FFF) << 15) \
                    | ((unsigned long long)((wr[(I)+2] >> (5 * (J))) & 0x7FFF) << 30); \
                unsigned nb =  (unsigned)((V & cm[(I)][(J)][0]) == 0ull)        \
                            | ((unsigned)((V & cm[(I)][(J)][1]) == 0ull) << 1)  \
                            | ((unsigned)((V & cm[(I)][(J)][2]) == 0ull) << 2)  \
                            | ((unsigned)((V & cm[(I)][(J)][3]) == 0ull) << 3)  \
                            | ((unsigned)((V & cm[(I)][(J)][4]) == 0ull) << 4); \
                unsigned sh = 5u * ((J) + 1);                                   \
                if (nb != ((wr[(I)+1] >> sh) & 0x1Fu)) {                        \
                    wr[(I)+1] = (wr[(I)+1] & ~(0x1Fu << sh)) | (nb << sh);      \
                    act_s[pcB + (I) * PW2 + (J)] = (unsigned char)nb;           \
                    if ((I) == 0) rch0 = true; else rch1 = true;                \
                }                                                               \
            } while (0)

            switch (pass & 3) {              // cycle 4 diagonal sweep orders
            case 0:  // down-right
                EVAL(0,0); EVAL(0,1); EVAL(0,2); EVAL(0,3);
                EVAL(1,0); EVAL(1,1); EVAL(1,2); EVAL(1,3); break;
            case 1:  // up-left
                EVAL(1,3); EVAL(1,2); EVAL(1,1); EVAL(1,0);
                EVAL(0,3); EVAL(0,2); EVAL(0,1); EVAL(0,0); break;
            case 2:  // down-left
                EVAL(0,3); EVAL(0,2); EVAL(0,1); EVAL(0,0);
                EVAL(1,3); EVAL(1,2); EVAL(1,1); EVAL(1,0); break;
            default: // up-right
                EVAL(1,0); EVAL(1,1); EVAL(1,2); EVAL(1,3);
                EVAL(0,0); EVAL(0,1); EVAL(0,2); EVAL(0,3); break;
            }
            #undef EVAL

            if (rch0) { rowflag[pcur][gy0 + 1] = 1u; mych = true; }  // benign race
            if (rch1) { rowflag[pcur][gy0 + 2] = 1u; mych = true; }
        }
        if (__syncthreads_count(mych ? 1 : 0) == 0) break;
        int t0 = pprev; pprev = pcur; pcur = pnext; pnext = t0;
    }

    // writeback: zero scores of suppressed boxes (coords+scores written by k1)
    if (wk) {
        #pragma unroll
        for (int i = 0; i < 2; ++i)
            #pragma unroll
            for (int j = 0; j < 4; ++j) {
                unsigned bits = act_s[pcB + i * PW2 + j];
                int cell = (gy0 + i) * GW + gx0 + j;
                #pragma unroll
                for (int b = 0; b < NB; ++b)
                    if (!((bits >> b) & 1u)) out[(cell * NB + b) * 5 + 4] = 0.0f;
            }
    }
}

extern "C" void kernel_launch(void* const* d_in, const int* in_sizes, int n_in,
                              void* d_out, int out_size, void* d_ws, size_t ws_size,
                              hipStream_t stream) {
    const float* x = (const float*)d_in[0];
    float* out = (float*)d_out;

    // ws layout: masks u64[NB][NCELL] plane-major (108160 B)
    unsigned long long* masks = (unsigned long long*)d_ws;

    decode_adj_kernel<<<NTX * NTY, 192, 0, stream>>>(x, out, masks);
    nms_kernel<<<1, BLK2, 0, stream>>>(masks, out);
}